// Round 5
// baseline (584.283 us; speedup 1.0000x reference)
//
#include <hip/hip_runtime.h>
#include <stdint.h>

// Problem constants: N=500000, D_IN=128, R=256, D_OUT=64, U=10000
#define N_ROWS 500000
#define U_DIM 10000
#define EPSV 1e-8f
#define NT16 31250            // 16-row wave-tiles (exact: 500000/16)

typedef __attribute__((ext_vector_type(8))) short bf16x8;   // 8 bf16 = 4 VGPRs
typedef __attribute__((ext_vector_type(4))) float f32x4;    // MFMA 16x16 accumulator

__device__ __forceinline__ short f2bf(float f) {
  unsigned u = __float_as_uint(f);
  u += 0x7fffu + ((u >> 16) & 1u);
  return (short)(u >> 16);
}

// Packed weight layouts in d_ws (shorts), frag-major (one wave load = 1 KB):
//   L0: [rc=8][mat=2][ct=2][kt=4][lane=64][u=8]  @ 0      (128 KB; 16 KB/rc chunk)
//       (A-frag == B-frag lane layout, so identical to previous rounds)
//   L1: [rc=8][ct1=4][mat=3][lane=64][u=8]       @ 65536  (96 KB)
//       K-rows permuted by pi: hidden jl (0..31) sits at lane q=(jl>>2)&3,
//       slot u=((jl>>4)<<2)|(jl&3), matching the operand-swapped L0 output
//       layout (thread (n,q) holds hidden cols ct*16+q*4+reg of X-row n).
__global__ void prep_weights(const float* __restrict__ Wmu0,
                             const float* __restrict__ Wlv0,
                             const float* __restrict__ Wmu1,
                             const float* __restrict__ Wlv1,
                             short* __restrict__ wgt) {
  int i = blockIdx.x * blockDim.x + threadIdx.x;
  if (i < 32768) {                       // L0 element: k = i>>8 (0..127), c = i&255
    int c = i & 255, k = i >> 8;
    int rc = c >> 5, ct = (c >> 4) & 1, n = c & 15;
    int kt = k >> 5, q = (k >> 3) & 3, u = k & 7;
    int lane = q * 16 + n;
    float mu = Wmu0[k * 256 + c];
    float ev = __expf(Wlv0[k * 256 + c]);
    wgt[((((rc * 2 + 0) * 2 + ct) * 4 + kt) * 64 + lane) * 8 + u] = f2bf(mu);
    wgt[((((rc * 2 + 1) * 2 + ct) * 4 + kt) * 64 + lane) * 8 + u] = f2bf(ev);
  } else if (i < 49152) {                // L1 element: j = (i-32768)>>6, o = &63
    int i2 = i - 32768;
    int o = i2 & 63, j = i2 >> 6;
    int rc = j >> 5, jl = j & 31;
    int q = (jl >> 2) & 3;                         // pi-permuted K placement
    int u = ((jl >> 4) << 2) | (jl & 3);
    int ct1 = o >> 4, n = o & 15;
    int lane = q * 16 + n;
    float mu = Wmu1[j * 64 + o];
    float ev = __expf(Wlv1[j * 64 + o]);
    int b = 65536 + (((rc * 4 + ct1) * 3 + 0) * 64 + lane) * 8 + u;
    wgt[b]        = f2bf(mu);            // mat 0: mu1
    wgt[b + 512]  = f2bf(mu * mu + ev);  // mat 1: mu1^2 + var
    wgt[b + 1024] = f2bf(ev);            // mat 2: var
  }
}

// Fused 2-layer VB kernel — R8: operand-swapped L0 (A=weights, B=X).
// Kills the per-rc LDS transpose round-trip that sat on the serial chain
// between the two layers: L0's D now has X-row = lane&15 (lane-local), so
// the gated activations ARE the L1 A-frag (under pi, folded into the L1
// weight packing). Evidence trail: R7 (+1 block/CU, 42% occ) was exactly
// neutral -> not wave-count-limited; no pipe >36% -> per-rc serial chain
// is binding; the transpose write+lgkm+read (~200 cyc/rc + 10M bank
// conflicts) was the largest removable chain link. LDS now 32 KB (stage
// only) -> 5 blocks/CU (LDS-limited; launch_bounds (256,4) keeps the
// 128-VGPR cap so no spill risk - actual usage ~64).
__global__ __launch_bounds__(256, 4) void vb_fused(
    const float* __restrict__ X, const int* __restrict__ Xidx,
    const short* __restrict__ wgt, float* __restrict__ out) {
  __shared__ __align__(16) short stage[2][8192];   // 2 x 16 KB L0 chunk (all LDS)

  const int tid  = threadIdx.x;
  const int w    = tid >> 6;
  const int lane = tid & 63;
  const int n    = lane & 15;
  const int q    = lane >> 4;
  const int T    = blockIdx.x * 4 + w;             // wave-tile id
  const bool active = (T < NT16);
  const int row0 = active ? T * 16 : (N_ROWS - 16);  // tail waves: dup rows, no atomics

  const f32x4 zf4 = {0.f, 0.f, 0.f, 0.f};
  const int lane8 = lane * 8;

  // ---- X prologue: 16 rows once, pre-convert to bf16 B-frags (32 VGPRs)
  // (same per-lane elements as the old A-frags: row n, cols kt*32+q*8+u)
  bf16x8 a_m[4], a_sq[4];
  {
    const float* xr = X + (size_t)(row0 + n) * 128;
#pragma unroll
    for (int kt = 0; kt < 4; ++kt) {
      float xf[8];
      *(float4*)&xf[0] = *(const float4*)&xr[kt * 32 + q * 8];
      *(float4*)&xf[4] = *(const float4*)&xr[kt * 32 + q * 8 + 4];
#pragma unroll
      for (int u = 0; u < 8; ++u) {
        a_m[kt][u]  = f2bf(xf[u]);
        a_sq[kt][u] = f2bf(xf[u] * xf[u]);
      }
    }
  }

  f32x4 accm1[4], accv1[4];
#pragma unroll
  for (int c = 0; c < 4; ++c) { accm1[c] = zf4; accv1[c] = zf4; }

  // ---- async staging: 4 segments x (256 thr x 16 B) = 16 KB per rc-chunk.
  const char* gbase = (const char*)wgt;
#define ISSUE_STAGE(rc_, buf_)                                                 \
  do {                                                                         \
    _Pragma("unroll")                                                          \
    for (int s_ = 0; s_ < 4; ++s_) {                                           \
      __builtin_amdgcn_global_load_lds(                                        \
          (const __attribute__((address_space(1))) unsigned int*)              \
              (gbase + (rc_) * 16384 + s_ * 4096 + tid * 16),                  \
          (__attribute__((address_space(3))) unsigned int*)                    \
              ((char*)&stage[buf_][0] + s_ * 4096 + (w << 10)),                \
          16, 0, 0);                                                           \
    }                                                                          \
  } while (0)

  ISSUE_STAGE(0, 0);

#pragma unroll
  for (int rc = 0; rc < 8; ++rc) {
    // barrier: compiler drains vmcnt(0) before s_barrier -> stage[rc&1] is
    // complete+visible; all waves have finished reading stage[(rc+1)&1]
    // (their reads were iteration rc-1, lgkmcnt drained before the barrier).
    __syncthreads();
    if (rc < 7) ISSUE_STAGE(rc + 1, (rc + 1) & 1);

    const short* st = &stage[rc & 1][0];

    // -- layer 0 partial, OPERAND-SWAPPED: A = weights (LDS), B = X (regs).
    // D[m = hidden c][n = X row]: thread (n,q) holds X-row n, hidden col
    // ct*16 + q*4 + reg in accm0[ct][reg].
    f32x4 accm0[2], accv0[2];
    accm0[0] = zf4; accm0[1] = zf4; accv0[0] = zf4; accv0[1] = zf4;
#pragma unroll
    for (int kt = 0; kt < 4; ++kt) {
#pragma unroll
      for (int ct = 0; ct < 2; ++ct) {
        bf16x8 bm = *(const bf16x8*)&st[((0 * 2 + ct) * 4 + kt) * 512 + lane8];
        bf16x8 bv = *(const bf16x8*)&st[((1 * 2 + ct) * 4 + kt) * 512 + lane8];
        accm0[ct] = __builtin_amdgcn_mfma_f32_16x16x32_bf16(bm, a_m[kt],  accm0[ct], 0, 0, 0);
        accv0[ct] = __builtin_amdgcn_mfma_f32_16x16x32_bf16(bv, a_sq[kt], accv0[ct], 0, 0, 0);
      }
    }

    // -- gate + convert, ALL IN REGISTERS (no LDS round-trip):
    // L1 A-frag slot u <- hidden col (u>>2)*16 + q*4 + (u&3) = accm0[u>>2][u&3]
    bf16x8 am, av, asq;
#pragma unroll
    for (int u = 0; u < 8; ++u) {
      float m = accm0[u >> 2][u & 3];
      float v = accv0[u >> 2][u & 3];
      if (!(m > 0.f)) { m = 0.f; v = 0.f; }
      am[u]  = f2bf(m);
      av[u]  = f2bf(v);
      asq[u] = f2bf(m * m);
    }

    // -- layer 1 partial: weights from global (packed 1 KB frags, L1-resident,
    // K-rows pi-permuted at prep time to match the register layout)
    const short* l1b = wgt + 65536 + rc * 6144 + lane8;
#pragma unroll
    for (int ct1 = 0; ct1 < 4; ++ct1) {
      const short* fb = l1b + ct1 * 1536;
      bf16x8 b1 = *(const bf16x8*)&fb[0];
      bf16x8 b2 = *(const bf16x8*)&fb[512];
      bf16x8 b3 = *(const bf16x8*)&fb[1024];
      accm1[ct1] = __builtin_amdgcn_mfma_f32_16x16x32_bf16(am,  b1, accm1[ct1], 0, 0, 0);
      accv1[ct1] = __builtin_amdgcn_mfma_f32_16x16x32_bf16(av,  b2, accv1[ct1], 0, 0, 0);
      accv1[ct1] = __builtin_amdgcn_mfma_f32_16x16x32_bf16(asq, b3, accv1[ct1], 0, 0, 0);
    }
  }
#undef ISSUE_STAGE

  // ---- epilogue: run-aggregated segment atomics (tail-dup waves skip)
  // L1 D layout unchanged: thread (n,q) holds out col n (per ct1 tile),
  // X rows q*4+reg.
  if (!active) return;
  float* meanp = out;
  float* varp  = out + U_DIM * 64;
  int4 idx4 = *(const int4*)&Xidx[row0 + q * 4];
  int uid[4] = {idx4.x, idx4.y, idx4.z, idx4.w};
#pragma unroll
  for (int ct = 0; ct < 4; ++ct) {
    const int o = ct * 16 + n;
    float sm = 0.f, sv = 0.f;
    int cur = uid[0];
#pragma unroll
    for (int reg = 0; reg < 4; ++reg) {
      float v1 = fmaxf(accv1[ct][reg], EPSV);
      float inv = 1.0f / v1;
      float mi  = accm1[ct][reg] * inv;
      if (uid[reg] != cur) {
        atomicAdd(&meanp[cur * 64 + o], sm);
        atomicAdd(&varp[cur * 64 + o], sv);
        sm = 0.f; sv = 0.f; cur = uid[reg];
      }
      sm += mi; sv += inv;
    }
    atomicAdd(&meanp[cur * 64 + o], sm);
    atomicAdd(&varp[cur * 64 + o], sv);
  }
}

// emb_var = 1/(sum_inv + eps); emb_mean = sum_m_inv * emb_var  (in place)
__global__ void finalize(float* __restrict__ out) {
  int i = blockIdx.x * blockDim.x + threadIdx.x;
  if (i < U_DIM * 64) {
    float s = out[U_DIM * 64 + i];
    float var = 1.0f / (s + EPSV);
    out[U_DIM * 64 + i] = var;
    out[i] = out[i] * var;
  }
}

extern "C" void kernel_launch(void* const* d_in, const int* in_sizes, int n_in,
                              void* d_out, int out_size, void* d_ws, size_t ws_size,
                              hipStream_t stream) {
  (void)in_sizes; (void)n_in; (void)out_size; (void)ws_size;
  const float* X    = (const float*)d_in[0];
  const int*   Xidx = (const int*)d_in[1];
  const float* Wmu0 = (const float*)d_in[2];
  const float* Wlv0 = (const float*)d_in[3];
  const float* Wmu1 = (const float*)d_in[4];
  const float* Wlv1 = (const float*)d_in[5];
  float* out = (float*)d_out;
  short* wgt = (short*)d_ws;            // 224 KB workspace (packed weights)

  hipMemsetAsync(d_out, 0, (size_t)U_DIM * 64 * 2 * sizeof(float), stream);
  prep_weights<<<192, 256, 0, stream>>>(Wmu0, Wlv0, Wmu1, Wlv1, wgt);
  // 31250 16-row wave-tiles / 4 per block -> 7813 blocks (tail clamped+guarded)
  vb_fused<<<7813, 256, 0, stream>>>(X, Xidx, wgt, out);
  finalize<<<(U_DIM * 64 + 255) / 256, 256, 0, stream>>>(out);
}